// Round 7
// baseline (481.041 us; speedup 1.0000x reference)
//
#include <hip/hip_runtime.h>
#include <hip/hip_bf16.h>
#include <cmath>

#define BATCH 4
#define SEQ 2048
#define DM 1024
#define NS 16
#define M_ROWS (BATCH * SEQ)

typedef short bf16x8 __attribute__((ext_vector_type(8)));
typedef short bf16x4 __attribute__((ext_vector_type(4)));
typedef float f32x4 __attribute__((ext_vector_type(4)));

// fp32 -> bf16 round-to-nearest-even
__device__ __forceinline__ short f2bf(float f) {
    union { float f; unsigned u; } a; a.f = f;
    unsigned u = a.u;
    return (short)((u + 0x7fffu + ((u >> 16) & 1u)) >> 16);
}
__device__ __forceinline__ float bf2f(unsigned short s) {
    union { unsigned u; float f; } a; a.u = ((unsigned)s) << 16;
    return a.f;
}

#define LDS_CAST(p) ((__attribute__((address_space(3))) unsigned*)(p))
#define GLB_CAST(p) ((const __attribute__((address_space(1))) unsigned*)(p))

// ---------------------------------------------------------------------------
// Kernel 0: convert x, W1, W2, W3 fp32 -> bf16. Block-uniform segment select.
// Wcb = [W2(16 rows); W3(16 rows)], row-major, K contiguous.  (~15 us)
// ---------------------------------------------------------------------------
__global__ void __launch_bounds__(256) convert_all(
    const float* __restrict__ x,  const float* __restrict__ W1,
    const float* __restrict__ W2, const float* __restrict__ W3,
    short* __restrict__ xb, short* __restrict__ W1b, short* __restrict__ Wcb)
{
    const int b = blockIdx.x;
    const int t = threadIdx.x;
    const float4* src; bf16x4* dst; int qbase;
    if (b < 2048)      { src = (const float4*)x;  dst = (bf16x4*)xb;  qbase = b * 1024; }
    else if (b < 2304) { src = (const float4*)W1; dst = (bf16x4*)W1b; qbase = (b - 2048) * 1024; }
    else if (b < 2308) { src = (const float4*)W2; dst = (bf16x4*)Wcb; qbase = (b - 2304) * 1024; }
    else               { src = (const float4*)W3; dst = (bf16x4*)(Wcb + NS * DM); qbase = (b - 2308) * 1024; }
    #pragma unroll
    for (int i = 0; i < 4; i++) {
        int q = qbase + i * 256 + t;
        float4 v = src[q];
        bf16x4 s;
        s.x = f2bf(v.x); s.y = f2bf(v.y); s.z = f2bf(v.z); s.w = f2bf(v.w);
        dst[q] = s;
    }
}

// ---------------------------------------------------------------------------
// Kernel 1: fused  z = xb @ W1b^T  (128x128 tile, BK=64, single-buffer,
// fully-unrolled K, global_load_lds w/ global-side XOR swizzle — m97-style
// 2-barrier structure; dbuf reverted per R6 regression),
// bc = sum_n (B+b2)(C+b3) in-loop: wave w covers bc rows wm+(w&1)*32+{0..31}
// reusing its own af fragments against Wc,
// epilogue y = x * softplus(z+b1) * bc (fast softplus).
// BK=64 8-chunk swizzle: 0 LDS bank conflicts (verified R3/R5).
// ---------------------------------------------------------------------------
__global__ void __launch_bounds__(256) gemm_fused(
    const short* __restrict__ xb, const short* __restrict__ W1b,
    const short* __restrict__ Wcb, const float* __restrict__ b1,
    const float* __restrict__ b2,  const float* __restrict__ b3,
    float* __restrict__ out)
{
    __shared__ short As[128][64];    // 16 KB  x tile   [m][k]
    __shared__ short Bs[128][64];    // 16 KB  W1 tile  [n][k]
    __shared__ short Wcs[32][64];    //  4 KB  Wc tile  [n][k]
    __shared__ float bcs[128];

    const int n0 = blockIdx.x * 128;
    const int m0 = blockIdx.y * 128;
    const int t = threadIdx.x;
    const int lane = t & 63;
    const int w = t >> 6;
    const int wm = (w >> 1) * 64;
    const int wn = (w & 1) * 64;
    const int lm = lane & 15;
    const int quad = lane >> 4;

    // staging: 8 chunks of 16B per 64-element row; 32-row groups
    const int sr  = t >> 3;               // 0..31
    const int sc  = t & 7;                // 0..7
    const int gch = (sc ^ (sr & 7)) * 8;  // swizzled k-element offset

    // loop-invariant staging pointers (row-group + kk*64 added as constants)
    const short* pa = xb  + (size_t)(m0 + sr) * DM + gch;
    const short* pb = W1b + (size_t)(n0 + sr) * DM + gch;
    const short* pw = Wcb + (size_t)sr        * DM + gch;

    f32x4 acc[4][4] = {};    // main: 64 AGPRs
    f32x4 abc[2][2] = {};    // bc:   [i2][h] h=0:W2 h=1:W3, 16 AGPRs

    #pragma unroll
    for (int kk = 0; kk < 16; kk++) {
        const int ke = kk * 64;          // element offset, constant per iter
        #pragma unroll
        for (int u = 0; u < 4; u++) {
            __builtin_amdgcn_global_load_lds(GLB_CAST(pa + (size_t)u * 32 * DM + ke),
                LDS_CAST(&As[u * 32 + sr][sc * 8]), 16, 0, 0);
            __builtin_amdgcn_global_load_lds(GLB_CAST(pb + (size_t)u * 32 * DM + ke),
                LDS_CAST(&Bs[u * 32 + sr][sc * 8]), 16, 0, 0);
        }
        __builtin_amdgcn_global_load_lds(GLB_CAST(pw + ke),
            LDS_CAST(&Wcs[sr][sc * 8]), 16, 0, 0);
        __syncthreads();

        #pragma unroll
        for (int ks = 0; ks < 2; ks++) {
            // all fragment rows have (row&7) == (lm&7) -> shared chunk index
            const int cs = ((ks * 4 + quad) ^ (lm & 7)) * 8;
            bf16x8 af[4], bfv[4], wcv[2];
            #pragma unroll
            for (int i = 0; i < 4; i++)
                af[i] = *(const bf16x8*)&As[wm + i * 16 + lm][cs];
            #pragma unroll
            for (int j = 0; j < 4; j++)
                bfv[j] = *(const bf16x8*)&Bs[wn + j * 16 + lm][cs];
            #pragma unroll
            for (int h = 0; h < 2; h++)
                wcv[h] = *(const bf16x8*)&Wcs[h * 16 + lm][cs];

            #pragma unroll
            for (int i = 0; i < 4; i++)
                #pragma unroll
                for (int j = 0; j < 4; j++)
                    acc[i][j] = __builtin_amdgcn_mfma_f32_16x16x32_bf16(
                        af[i], bfv[j], acc[i][j], 0, 0, 0);
            // bc: wave w owns m-rows wm+(w&1)*32 + {0..31} via af[(w&1)*2 + i2]
            #pragma unroll
            for (int i2 = 0; i2 < 2; i2++)
                #pragma unroll
                for (int h = 0; h < 2; h++)
                    abc[i2][h] = __builtin_amdgcn_mfma_f32_16x16x32_bf16(
                        af[(w & 1) * 2 + i2], wcv[h], abc[i2][h], 0, 0, 0);
        }
        __syncthreads();
    }

    // ---- bc reduce: abc[i2][h], n=lm, m-row = wm+(w&1)*32+i2*16+quad*4+r ----
    float bb2 = b2[lm], bb3 = b3[lm];
    #pragma unroll
    for (int i2 = 0; i2 < 2; i2++) {
        #pragma unroll
        for (int r = 0; r < 4; r++) {
            float p = (abc[i2][0][r] + bb2) * (abc[i2][1][r] + bb3);
            p += __shfl_xor(p, 1);
            p += __shfl_xor(p, 2);
            p += __shfl_xor(p, 4);
            p += __shfl_xor(p, 8);
            if (lm == 0) bcs[wm + (w & 1) * 32 + i2 * 16 + quad * 4 + r] = p;
        }
    }
    __syncthreads();

    // ---- epilogue: D col(n)=lm, row(m)=quad*4+r; fast stable softplus ----
    const unsigned short* xbu = (const unsigned short*)xb;
    float b1v[4];
    #pragma unroll
    for (int j = 0; j < 4; j++) b1v[j] = b1[n0 + wn + j * 16 + lm];

    #pragma unroll
    for (int i = 0; i < 4; i++) {
        #pragma unroll
        for (int r = 0; r < 4; r++) {
            int lrow = wm + i * 16 + quad * 4 + r;
            int gm = m0 + lrow;
            float bcv = bcs[lrow];
            const unsigned short* xrow = xbu + (size_t)gm * DM + n0 + wn + lm;
            float* orow = out + (size_t)gm * DM + n0 + wn + lm;
            #pragma unroll
            for (int j = 0; j < 4; j++) {
                float z = acc[i][j][r] + b1v[j];
                float az = __builtin_fabsf(z);
                float sp = fmaxf(z, 0.f) + __logf(1.f + __expf(-az));
                orow[j * 16] = bf2f(xrow[j * 16]) * sp * bcv;
            }
        }
    }
}

extern "C" void kernel_launch(void* const* d_in, const int* in_sizes, int n_in,
                              void* d_out, int out_size, void* d_ws, size_t ws_size,
                              hipStream_t stream) {
    const float* x  = (const float*)d_in[0];
    const float* W1 = (const float*)d_in[1];
    const float* b1 = (const float*)d_in[2];
    const float* W2 = (const float*)d_in[3];
    const float* b2 = (const float*)d_in[4];
    const float* W3 = (const float*)d_in[5];
    const float* b3 = (const float*)d_in[6];
    // d_in[7] = A is dead math
    float* out = (float*)d_out;

    // ws: xb 16 MiB @0 | W1b 2 MiB @16M | Wcb 64 KiB @18M
    char* ws = (char*)d_ws;
    short* xb  = (short*)(ws);
    short* W1b = (short*)(ws + (size_t)16 * 1024 * 1024);
    short* Wcb = (short*)(ws + (size_t)18 * 1024 * 1024);

    convert_all<<<2312, 256, 0, stream>>>(x, W1, W2, W3, xb, W1b, Wcb);

    // grid (8,64): linear id % 8 == n-block -> each XCD sees one W1b slice
    dim3 grid(DM / 128, M_ROWS / 128);
    gemm_fused<<<grid, 256, 0, stream>>>(xb, W1b, Wcb, b1, b2, b3, out);
}

// Round 8
// 124.858 us; speedup vs baseline: 3.8527x; 3.8527x over previous
//
#include <hip/hip_runtime.h>
#include <hip/hip_bf16.h>
#include <cmath>

#define BATCH 4
#define SEQ 2048
#define DM 1024
#define NS 16
#define M_ROWS (BATCH * SEQ)

typedef short bf16x8 __attribute__((ext_vector_type(8)));
typedef short bf16x4 __attribute__((ext_vector_type(4)));
typedef float f32x4 __attribute__((ext_vector_type(4)));

// fp32 -> bf16 round-to-nearest-even
__device__ __forceinline__ short f2bf(float f) {
    union { float f; unsigned u; } a; a.f = f;
    unsigned u = a.u;
    return (short)((u + 0x7fffu + ((u >> 16) & 1u)) >> 16);
}
__device__ __forceinline__ float bf2f(unsigned short s) {
    union { unsigned u; float f; } a; a.u = ((unsigned)s) << 16;
    return a.f;
}

#define LDS_CAST(p) ((__attribute__((address_space(3))) unsigned*)(p))
#define GLB_CAST(p) ((const __attribute__((address_space(1))) unsigned*)(p))

// ---------------------------------------------------------------------------
// Kernel 0: convert x, W1, W2, W3 fp32 -> bf16. Block-uniform segment select.
// Wcb = [W2(16 rows); W3(16 rows)], row-major, K contiguous.  (~15 us)
// ---------------------------------------------------------------------------
__global__ void __launch_bounds__(256) convert_all(
    const float* __restrict__ x,  const float* __restrict__ W1,
    const float* __restrict__ W2, const float* __restrict__ W3,
    short* __restrict__ xb, short* __restrict__ W1b, short* __restrict__ Wcb)
{
    const int b = blockIdx.x;
    const int t = threadIdx.x;
    const float4* src; bf16x4* dst; int qbase;
    if (b < 2048)      { src = (const float4*)x;  dst = (bf16x4*)xb;  qbase = b * 1024; }
    else if (b < 2304) { src = (const float4*)W1; dst = (bf16x4*)W1b; qbase = (b - 2048) * 1024; }
    else if (b < 2308) { src = (const float4*)W2; dst = (bf16x4*)Wcb; qbase = (b - 2304) * 1024; }
    else               { src = (const float4*)W3; dst = (bf16x4*)(Wcb + NS * DM); qbase = (b - 2308) * 1024; }
    #pragma unroll
    for (int i = 0; i < 4; i++) {
        int q = qbase + i * 256 + t;
        float4 v = src[q];
        bf16x4 s;
        s.x = f2bf(v.x); s.y = f2bf(v.y); s.z = f2bf(v.z); s.w = f2bf(v.w);
        dst[q] = s;
    }
}

// ---------------------------------------------------------------------------
// Kernel 1: fused  z = xb @ W1b^T  (128x128 tile, BK=64, single-buffer,
// fully-unrolled K, global_load_lds w/ global-side XOR swizzle),
// bc = sum_n (B+b2)(C+b3) in-loop: the two waves sharing an m-half split its
// 64 bc rows; fragment choice via WAVE-UNIFORM branch with CONSTANT indices
// (R7's dynamic af[] index demoted the fragment array to scratch — 8x slow),
// epilogue y = x * softplus(z+b1) * bc (fast softplus).
// ---------------------------------------------------------------------------
__global__ void __launch_bounds__(256) gemm_fused(
    const short* __restrict__ xb, const short* __restrict__ W1b,
    const short* __restrict__ Wcb, const float* __restrict__ b1,
    const float* __restrict__ b2,  const float* __restrict__ b3,
    float* __restrict__ out)
{
    __shared__ short As[128][64];    // 16 KB  x tile   [m][k]
    __shared__ short Bs[128][64];    // 16 KB  W1 tile  [n][k]
    __shared__ short Wcs[32][64];    //  4 KB  Wc tile  [n][k]
    __shared__ float bcs[128];

    const int n0 = blockIdx.x * 128;
    const int m0 = blockIdx.y * 128;
    const int t = threadIdx.x;
    const int lane = t & 63;
    const int w = t >> 6;
    const int wm = (w >> 1) * 64;
    const int wn = (w & 1) * 64;
    const int lm = lane & 15;
    const int quad = lane >> 4;

    // staging: 8 chunks of 16B per 64-element row; 32-row groups
    const int sr  = t >> 3;               // 0..31
    const int sc  = t & 7;                // 0..7
    const int gch = (sc ^ (sr & 7)) * 8;  // swizzled k-element offset

    // loop-invariant staging pointers (row-group + kk*64 added as constants)
    const short* pa = xb  + (size_t)(m0 + sr) * DM + gch;
    const short* pb = W1b + (size_t)(n0 + sr) * DM + gch;
    const short* pw = Wcb + (size_t)sr        * DM + gch;

    f32x4 acc[4][4] = {};    // main accumulators
    f32x4 abc[2][2] = {};    // bc: [i2][h] h=0:W2 h=1:W3

    #pragma unroll
    for (int kk = 0; kk < 16; kk++) {
        const int ke = kk * 64;          // element offset, constant per iter
        #pragma unroll
        for (int u = 0; u < 4; u++) {
            __builtin_amdgcn_global_load_lds(GLB_CAST(pa + (size_t)u * 32 * DM + ke),
                LDS_CAST(&As[u * 32 + sr][sc * 8]), 16, 0, 0);
            __builtin_amdgcn_global_load_lds(GLB_CAST(pb + (size_t)u * 32 * DM + ke),
                LDS_CAST(&Bs[u * 32 + sr][sc * 8]), 16, 0, 0);
        }
        __builtin_amdgcn_global_load_lds(GLB_CAST(pw + ke),
            LDS_CAST(&Wcs[sr][sc * 8]), 16, 0, 0);
        __syncthreads();

        #pragma unroll
        for (int ks = 0; ks < 2; ks++) {
            // all fragment rows have (row&7) == (lm&7) -> shared chunk index
            const int cs = ((ks * 4 + quad) ^ (lm & 7)) * 8;
            bf16x8 af[4], bfv[4], wcv[2];
            #pragma unroll
            for (int i = 0; i < 4; i++)
                af[i] = *(const bf16x8*)&As[wm + i * 16 + lm][cs];
            #pragma unroll
            for (int j = 0; j < 4; j++)
                bfv[j] = *(const bf16x8*)&Bs[wn + j * 16 + lm][cs];
            #pragma unroll
            for (int h = 0; h < 2; h++)
                wcv[h] = *(const bf16x8*)&Wcs[h * 16 + lm][cs];

            #pragma unroll
            for (int i = 0; i < 4; i++)
                #pragma unroll
                for (int j = 0; j < 4; j++)
                    acc[i][j] = __builtin_amdgcn_mfma_f32_16x16x32_bf16(
                        af[i], bfv[j], acc[i][j], 0, 0, 0);

            // bc: the two waves with the same wm split its 64 rows.
            // WAVE-UNIFORM branch, constant indices (keeps af in VGPRs).
            if (w & 1) {
                #pragma unroll
                for (int h = 0; h < 2; h++) {
                    abc[0][h] = __builtin_amdgcn_mfma_f32_16x16x32_bf16(
                        af[2], wcv[h], abc[0][h], 0, 0, 0);
                    abc[1][h] = __builtin_amdgcn_mfma_f32_16x16x32_bf16(
                        af[3], wcv[h], abc[1][h], 0, 0, 0);
                }
            } else {
                #pragma unroll
                for (int h = 0; h < 2; h++) {
                    abc[0][h] = __builtin_amdgcn_mfma_f32_16x16x32_bf16(
                        af[0], wcv[h], abc[0][h], 0, 0, 0);
                    abc[1][h] = __builtin_amdgcn_mfma_f32_16x16x32_bf16(
                        af[1], wcv[h], abc[1][h], 0, 0, 0);
                }
            }
        }
        __syncthreads();
    }

    // ---- bc reduce: abc[i2][h], n=lm, m-row = wm+(w&1)*32+i2*16+quad*4+r ----
    float bb2 = b2[lm], bb3 = b3[lm];
    #pragma unroll
    for (int i2 = 0; i2 < 2; i2++) {
        #pragma unroll
        for (int r = 0; r < 4; r++) {
            float p = (abc[i2][0][r] + bb2) * (abc[i2][1][r] + bb3);
            p += __shfl_xor(p, 1);
            p += __shfl_xor(p, 2);
            p += __shfl_xor(p, 4);
            p += __shfl_xor(p, 8);
            if (lm == 0) bcs[wm + (w & 1) * 32 + i2 * 16 + quad * 4 + r] = p;
        }
    }
    __syncthreads();

    // ---- epilogue: D col(n)=lm, row(m)=quad*4+r; fast stable softplus ----
    const unsigned short* xbu = (const unsigned short*)xb;
    float b1v[4];
    #pragma unroll
    for (int j = 0; j < 4; j++) b1v[j] = b1[n0 + wn + j * 16 + lm];

    #pragma unroll
    for (int i = 0; i < 4; i++) {
        #pragma unroll
        for (int r = 0; r < 4; r++) {
            int lrow = wm + i * 16 + quad * 4 + r;
            int gm = m0 + lrow;
            float bcv = bcs[lrow];
            const unsigned short* xrow = xbu + (size_t)gm * DM + n0 + wn + lm;
            float* orow = out + (size_t)gm * DM + n0 + wn + lm;
            #pragma unroll
            for (int j = 0; j < 4; j++) {
                float z = acc[i][j][r] + b1v[j];
                float az = __builtin_fabsf(z);
                float sp = fmaxf(z, 0.f) + __logf(1.f + __expf(-az));
                orow[j * 16] = bf2f(xrow[j * 16]) * sp * bcv;
            }
        }
    }
}

extern "C" void kernel_launch(void* const* d_in, const int* in_sizes, int n_in,
                              void* d_out, int out_size, void* d_ws, size_t ws_size,
                              hipStream_t stream) {
    const float* x  = (const float*)d_in[0];
    const float* W1 = (const float*)d_in[1];
    const float* b1 = (const float*)d_in[2];
    const float* W2 = (const float*)d_in[3];
    const float* b2 = (const float*)d_in[4];
    const float* W3 = (const float*)d_in[5];
    const float* b3 = (const float*)d_in[6];
    // d_in[7] = A is dead math
    float* out = (float*)d_out;

    // ws: xb 16 MiB @0 | W1b 2 MiB @16M | Wcb 64 KiB @18M
    char* ws = (char*)d_ws;
    short* xb  = (short*)(ws);
    short* W1b = (short*)(ws + (size_t)16 * 1024 * 1024);
    short* Wcb = (short*)(ws + (size_t)18 * 1024 * 1024);

    convert_all<<<2312, 256, 0, stream>>>(x, W1, W2, W3, xb, W1b, Wcb);

    // grid (8,64): linear id % 8 == n-block -> each XCD sees one W1b slice
    dim3 grid(DM / 128, M_ROWS / 128);
    gemm_fused<<<grid, 256, 0, stream>>>(xb, W1b, Wcb, b1, b2, b3, out);
}